// Round 5
// baseline (1143.699 us; speedup 1.0000x reference)
//
#include <hip/hip_runtime.h>
#include <hip/hip_bf16.h>
#include <stdint.h>

#define B_TOTAL 262144
#define TB 32
#define SLOT 8192           // 32 rows * 128 cols * 2B
#define BUF1 40960          // second bank: 5 slots
#define LDS_BYTES 81920     // 80 KiB -> 2 blocks/CU co-resident
#define HEAD_W 204800       // bf16 weight elements per head in d_ws

typedef short v8s __attribute__((ext_vector_type(8)));
typedef float v4f __attribute__((ext_vector_type(4)));

union Frag { uint4 q; uint32_t d[4]; v8s v; };

__device__ __forceinline__ uint32_t pack2(float a, float b) {
    union { __hip_bfloat162 h; uint32_t u; } p;
    p.h = __float22bfloat162_rn(make_float2(a, b));
    return p.u;
}

// LDS element [row][k] (bf16) at row*256 + ((k>>3) ^ (row&15))*16 + (k&7)*2

struct KParams {
    const float* x; const float* u; const float* mix; const float* P;
    const float* mb[6];
    const float* tb[6];
    const float* Wout[2];
    const float* bout[2];
    const unsigned short* wbf;
    float* out;
};

struct PrepParams { const float* src[12]; unsigned short* dst; };

__global__ __launch_bounds__(256) void prep_kernel(PrepParams pp) {
    const int ends[12] = {16384,81920,98304,163840,172032,204800,
                          221184,286720,303104,368640,376832,409600};
    int gi = (blockIdx.x * 256 + threadIdx.x) * 4;
    if (gi >= 409600) return;
    int s = 0;
    #pragma unroll
    for (int i = 0; i < 12; ++i) { if (gi >= ends[i]) s = i + 1; }
    int base = (s == 0) ? 0 : ends[s - 1];
    const float4 f = *(const float4*)(pp.src[s] + (gi - base));
    *(uint2*)(pp.dst + gi) = make_uint2(pack2(f.x, f.y), pack2(f.z, f.w));
}

__device__ __forceinline__ void stage_xu(char* lds, const float* x, const float* u,
                                         int rowBase, int tid)
{
    // 32 rows * 16 groups = 512 tasks, one per thread
    const int row = tid >> 4;
    const int gg  = tid & 15;
    const int grow = rowBase + row;
    float4 fa, fb;
    if (gg < 12) {
        const float* s2 = x + grow * 96 + gg * 8;
        fa = *(const float4*)s2; fb = *(const float4*)(s2 + 4);
    } else {
        const float* s2 = u + grow * 32 + (gg - 12) * 8;
        fa = *(const float4*)s2; fb = *(const float4*)(s2 + 4);
    }
    *(uint4*)(lds + row * 256 + ((gg ^ (row & 15)) << 4)) =
        make_uint4(pack2(fa.x, fa.y), pack2(fa.z, fa.w),
                   pack2(fb.x, fb.y), pack2(fb.z, fb.w));
}

// s=0 (main-stream) weight frags, loaded BEFORE the phase barrier so L2
// latency overlaps barrier wait + previous epilogue. Only 16 VGPRs.
struct WPre0 { Frag w0[4]; };

template<int N>
__device__ __forceinline__ WPre0 preload0(const unsigned short* W, int lane, int wave)
{
    WPre0 r;
    const int l15  = lane & 15;
    const int quad = lane >> 4;
    const int colBase = (N == 64) ? ((wave >> 1) << 4) : (wave << 4);
    const unsigned short* wRow = W + (colBase + l15) * 128 + quad * 8;
    #pragma unroll
    for (int ks = 0; ks < 4; ++ks)
        r.w0[ks].q = *(const uint4*)(wRow + ks * 32);
    return r;
}

// 8 waves, TB=32. N=128: wave = 16-col group, 2 row-tiles. N=64 (final):
// wave = (colgroup, row-tile), fused combine + Wout dot -> pgrid.
// MFMA: A = weight frag (m = out col), B = activation frag (n = batch row).
// Acc per lane: batch row bt*16+(lane&15), out cols obase+(lane>>4)*4+r.
// Weight frags double-buffered: stream s+1 loads issue before s's MFMAs.
template<bool SHARED_IN, int N>
__device__ __forceinline__ void compute(char* lds, int inOff, int outOff,
        const WPre0& wp, const unsigned short* W,
        const float* mbias, const float* tbias,
        float c0, const float* cP, int lane, int wave,
        const float* Wout, float* pgrid)
{
    constexpr bool FINAL = (N == 64);
    constexpr int NBT = FINAL ? 1 : 2;
    const int l15  = lane & 15;
    const int quad = lane >> 4;
    const int colBase = FINAL ? ((wave >> 1) << 4) : (wave << 4);
    const int btBase  = FINAL ? (wave & 1) : 0;
    const unsigned short* wRow = W + (colBase + l15) * 128 + quad * 8;

    v4f acc[5][NBT];
    #pragma unroll
    for (int s = 0; s < 5; ++s)
        #pragma unroll
        for (int bt = 0; bt < NBT; ++bt)
            acc[s][bt] = (v4f){0.f, 0.f, 0.f, 0.f};

    Frag wf[2][4];
    #pragma unroll
    for (int ks = 0; ks < 4; ++ks) wf[0][ks] = wp.w0[ks];

    Frag xS[4 * NBT];
    if constexpr (SHARED_IN) {
        #pragma unroll
        for (int ks = 0; ks < 4; ++ks) {
            const int gg = ks * 4 + quad;
            #pragma unroll
            for (int bt = 0; bt < NBT; ++bt) {
                const int row = (btBase + bt) * 16 + l15;
                xS[ks * NBT + bt].q =
                    *(const uint4*)(lds + inOff + row * 256 + ((gg ^ (row & 15)) << 4));
            }
        }
    }

    #pragma unroll
    for (int s = 0; s < 5; ++s) {
        if (s < 4) {
            #pragma unroll
            for (int ks = 0; ks < 4; ++ks)
                wf[(s + 1) & 1][ks].q =
                    *(const uint4*)(wRow + (s + 1) * (N * 128) + ks * 32);
        }
        #pragma unroll
        for (int ks = 0; ks < 4; ++ks) {
            const int gg = ks * 4 + quad;
            Frag xf[NBT];
            if constexpr (!SHARED_IN) {
                #pragma unroll
                for (int bt = 0; bt < NBT; ++bt) {
                    const int row = (btBase + bt) * 16 + l15;
                    xf[bt].q = *(const uint4*)(lds + inOff + s * SLOT + row * 256
                                               + ((gg ^ (row & 15)) << 4));
                }
            }
            #pragma unroll
            for (int bt = 0; bt < NBT; ++bt)
                acc[s][bt] = __builtin_amdgcn_mfma_f32_16x16x32_bf16(
                    wf[s & 1][ks].v,
                    (SHARED_IN ? xS[ks * NBT + bt].v : xf[bt].v),
                    acc[s][bt], 0, 0, 0);
        }
    }

    const int obase = colBase + quad * 4;
    const float4 mB = *(const float4*)(mbias + obase);
    float4 tB[4];
    #pragma unroll
    for (int s = 0; s < 4; ++s)
        tB[s] = *(const float4*)(tbias + s * N + obase);

    if constexpr (!FINAL) {
        #pragma unroll
        for (int bt = 0; bt < NBT; ++bt) {
            const int row = (btBase + bt) * 16 + l15;
            char* ab = lds + outOff + row * 256 + (((obase >> 3) ^ (row & 15)) << 4)
                       + ((obase & 7) << 1);
            float vr[4];
            vr[0] = c0 * (acc[0][bt][0] + mB.x);
            vr[1] = c0 * (acc[0][bt][1] + mB.y);
            vr[2] = c0 * (acc[0][bt][2] + mB.z);
            vr[3] = c0 * (acc[0][bt][3] + mB.w);
            uint2 tw[4];
            #pragma unroll
            for (int s = 0; s < 4; ++s) {
                float t0 = acc[s + 1][bt][0] + tB[s].x;
                float t1 = acc[s + 1][bt][1] + tB[s].y;
                float t2 = acc[s + 1][bt][2] + tB[s].z;
                float t3 = acc[s + 1][bt][3] + tB[s].w;
                vr[0] = fmaf(cP[s], t0, vr[0]);
                vr[1] = fmaf(cP[s], t1, vr[1]);
                vr[2] = fmaf(cP[s], t2, vr[2]);
                vr[3] = fmaf(cP[s], t3, vr[3]);
                tw[s] = make_uint2(pack2(fmaxf(t0, 0.f), fmaxf(t1, 0.f)),
                                   pack2(fmaxf(t2, 0.f), fmaxf(t3, 0.f)));
            }
            *(uint2*)ab = make_uint2(pack2(fmaxf(vr[0], 0.f), fmaxf(vr[1], 0.f)),
                                     pack2(fmaxf(vr[2], 0.f), fmaxf(vr[3], 0.f)));
            #pragma unroll
            for (int s = 0; s < 4; ++s)
                *(uint2*)(ab + (s + 1) * SLOT) = tw[s];
        }
    } else {
        const float4 wo = *(const float4*)(Wout + obase);
        float vr[4];
        vr[0] = c0 * (acc[0][0][0] + mB.x);
        vr[1] = c0 * (acc[0][0][1] + mB.y);
        vr[2] = c0 * (acc[0][0][2] + mB.z);
        vr[3] = c0 * (acc[0][0][3] + mB.w);
        #pragma unroll
        for (int s = 0; s < 4; ++s) {
            vr[0] = fmaf(cP[s], acc[s + 1][0][0] + tB[s].x, vr[0]);
            vr[1] = fmaf(cP[s], acc[s + 1][0][1] + tB[s].y, vr[1]);
            vr[2] = fmaf(cP[s], acc[s + 1][0][2] + tB[s].z, vr[2]);
            vr[3] = fmaf(cP[s], acc[s + 1][0][3] + tB[s].w, vr[3]);
        }
        float pp = fmaxf(vr[0], 0.f) * wo.x + fmaxf(vr[1], 0.f) * wo.y
                 + fmaxf(vr[2], 0.f) * wo.z + fmaxf(vr[3], 0.f) * wo.w;
        pp += __shfl_xor(pp, 16);
        pp += __shfl_xor(pp, 32);
        if (lane < 16)
            pgrid[(wave >> 1) * 32 + btBase * 16 + lane] = pp;
    }
}

extern "C" __global__ __launch_bounds__(512, 4)
void critic_kernel(KParams p)
{
    extern __shared__ char lds[];
    const int tid  = threadIdx.x;
    const int lane = tid & 63;
    const int wave = tid >> 6;
    const int rowBase = blockIdx.x * TB;

    const float m  = p.mix[0];
    const float c0 = 1.f - m;
    float cP[4];
    #pragma unroll
    for (int k = 0; k < 4; ++k) cP[k] = m * p.P[k];

    stage_xu(lds, p.x, p.u, rowBase, tid);

    #pragma unroll 1
    for (int head = 0; head < 2; ++head) {
        const unsigned short* wb = p.wbf + head * HEAD_W;
        const int hb = head * 3;

        WPre0 w1 = preload0<128>(wb, lane, wave);
        __syncthreads();
        // L1: xu (BUF0.slot0, shared) -> BUF1 (5 streams)
        compute<true, 128>(lds, 0, BUF1, w1, wb, p.mb[hb + 0], p.tb[hb + 0],
                           c0, cP, lane, wave, nullptr, nullptr);

        WPre0 w2 = preload0<128>(wb + 81920, lane, wave);
        __syncthreads();
        // L2: BUF1 -> BUF0 (overwrites xu slot)
        compute<false, 128>(lds, BUF1, 0, w2, wb + 81920, p.mb[hb + 1], p.tb[hb + 1],
                            c0, cP, lane, wave, nullptr, nullptr);

        WPre0 w3 = preload0<64>(wb + 163840, lane, wave);
        __syncthreads();
        // L3 + L4: BUF0 -> register combine -> dot(Wout) -> pgrid (in BUF1)
        compute<false, 64>(lds, 0, 0, w3, wb + 163840, p.mb[hb + 2], p.tb[hb + 2],
                           c0, cP, lane, wave, p.Wout[head], (float*)(lds + BUF1));
        __syncthreads();

        if (tid < TB) {
            const float* pg = (const float*)(lds + BUF1);
            p.out[head * B_TOTAL + rowBase + tid] =
                p.bout[head][0] + pg[tid] + pg[32 + tid] + pg[64 + tid] + pg[96 + tid];
        }
        if (head == 0)
            stage_xu(lds, p.x, p.u, rowBase, tid);   // L2 overwrote xu; restage
    }
}

extern "C" void kernel_launch(void* const* d_in, const int* in_sizes, int n_in,
                              void* d_out, int out_size, void* d_ws, size_t ws_size,
                              hipStream_t stream)
{
    (void)in_sizes; (void)n_in; (void)out_size; (void)ws_size;

    PrepParams pp;
    const int sidx[12] = {4, 20, 6, 22, 8, 24, 12, 26, 14, 28, 16, 30};
    for (int i = 0; i < 12; ++i) pp.src[i] = (const float*)d_in[sidx[i]];
    pp.dst = (unsigned short*)d_ws;

    KParams kp;
    kp.x = (const float*)d_in[0];  kp.u = (const float*)d_in[1];
    kp.mix = (const float*)d_in[2]; kp.P = (const float*)d_in[3];
    const int mbi[6] = {5, 7, 9, 13, 15, 17};
    const int tbi[6] = {21, 23, 25, 27, 29, 31};
    for (int i = 0; i < 6; ++i) {
        kp.mb[i] = (const float*)d_in[mbi[i]];
        kp.tb[i] = (const float*)d_in[tbi[i]];
    }
    kp.Wout[0] = (const float*)d_in[10]; kp.Wout[1] = (const float*)d_in[18];
    kp.bout[0] = (const float*)d_in[11]; kp.bout[1] = (const float*)d_in[19];
    kp.wbf = (const unsigned short*)d_ws;
    kp.out = (float*)d_out;

    (void)hipFuncSetAttribute((const void*)critic_kernel,
                              hipFuncAttributeMaxDynamicSharedMemorySize, LDS_BYTES);

    hipLaunchKernelGGL(prep_kernel, dim3(400), dim3(256), 0, stream, pp);
    hipLaunchKernelGGL(critic_kernel, dim3(8192), dim3(512), LDS_BYTES, stream, kp);
}

// Round 6
// 1118.426 us; speedup vs baseline: 1.0226x; 1.0226x over previous
//
#include <hip/hip_runtime.h>
#include <hip/hip_bf16.h>
#include <stdint.h>

#define B_TOTAL 262144
#define TB 32
#define SLOT 8192           // 32 rows * 128 cols * 2B
#define BUF1 40960          // second bank: 5 slots
#define LDS_BYTES 81920     // 80 KiB -> 2 blocks/CU co-resident
#define HEAD_W 204800       // bf16 weight elements per head in d_ws

typedef short v8s __attribute__((ext_vector_type(8)));
typedef float v4f __attribute__((ext_vector_type(4)));

union Frag { uint4 q; uint32_t d[4]; v8s v; };

__device__ __forceinline__ uint32_t pack2(float a, float b) {
    union { __hip_bfloat162 h; uint32_t u; } p;
    p.h = __float22bfloat162_rn(make_float2(a, b));
    return p.u;
}

// LDS activation element [row][k] (bf16) at row*256 + ((k>>3) ^ (row&15))*16 + (k&7)*2

struct KParams {
    const float* x; const float* u; const float* mix; const float* P;
    const float* mb[6];
    const float* tb[6];
    const float* Wout[2];
    const float* bout[2];
    const unsigned short* wbf;
    float* out;
};

struct PrepParams { const float* src[12]; unsigned short* dst; };

__global__ __launch_bounds__(256) void prep_kernel(PrepParams pp) {
    const int ends[12] = {16384,81920,98304,163840,172032,204800,
                          221184,286720,303104,368640,376832,409600};
    int gi = (blockIdx.x * 256 + threadIdx.x) * 4;
    if (gi >= 409600) return;
    int s = 0;
    #pragma unroll
    for (int i = 0; i < 12; ++i) { if (gi >= ends[i]) s = i + 1; }
    int base = (s == 0) ? 0 : ends[s - 1];
    const float4 f = *(const float4*)(pp.src[s] + (gi - base));
    *(uint2*)(pp.dst + gi) = make_uint2(pack2(f.x, f.y), pack2(f.z, f.w));
}

__device__ __forceinline__ void stage_xu(char* lds, const float* x, const float* u,
                                         int rowBase, int tid)
{
    #pragma unroll
    for (int G = tid; G < 512; G += 256) {
        const int row = G >> 4;
        const int gg  = G & 15;
        const int grow = rowBase + row;
        float4 fa, fb;
        if (gg < 12) {
            const float* s2 = x + grow * 96 + gg * 8;
            fa = *(const float4*)s2; fb = *(const float4*)(s2 + 4);
        } else {
            const float* s2 = u + grow * 32 + (gg - 12) * 8;
            fa = *(const float4*)s2; fb = *(const float4*)(s2 + 4);
        }
        *(uint4*)(lds + row * 256 + ((gg ^ (row & 15)) << 4)) =
            make_uint4(pack2(fa.x, fa.y), pack2(fa.z, fa.w),
                       pack2(fb.x, fb.y), pack2(fb.z, fb.w));
    }
}

// Preload j=0 (stream = wave) weight frags BEFORE the phase barrier: plain
// register loads, so vmcnt wait lands at first use (after barrier) -> L2
// latency overlaps barrier + previous epilogue.
template<int N>
__device__ __forceinline__ void preload(Frag* dst, const unsigned short* W,
                                        int lane, int wave)
{
    constexpr int OTC = N / 64;
    const int l15 = lane & 15, quad = lane >> 4;
    const unsigned short* Wj = W + wave * (N * 128);   // j=0 stream = wave (rotation)
    const int colBase = wave * (OTC * 16);
    #pragma unroll
    for (int ct = 0; ct < OTC; ++ct)
        #pragma unroll
        for (int ks = 0; ks < 4; ++ks)
            dst[ct * 4 + ks].q = *(const uint4*)(Wj + (colBase + ct * 16 + l15) * 128
                                                 + ks * 32 + quad * 8);
}

// 4 waves, TB=32. Wave = (OTc=2 colgroups = 32 cols) x (2 rowtiles = 32 rows)
// x 5 streams, processed in rotated order s_j = (j + wave) % 5 (de-phases the
// waves' weight bursts / LDS patterns). acc[j] combined uniformly:
// vr = sum_j coef[j]*(acc[j]+bias[j]) where coef = c0 for s==0 else m*P[s-1].
// MFMA: A = weight frag (m = out col), B = x frag (n = batch row).
// Acc per lane: batch row rt*16+(lane&15), out cols colBase+ct*16+(lane>>4)*4+r.
template<bool SHARED_IN, bool FINAL, int N>
__device__ __forceinline__ void compute(char* lds, int inOff, int outOff,
        const Frag* wpre, const unsigned short* W,
        const float* mbias, const float* tbias, const float* coef,
        int lane, int wave, const float* Wout, float* pgrid)
{
    constexpr int OTC = N / 64;
    constexpr int NW  = OTC * 4;
    const int l15 = lane & 15, quad = lane >> 4;
    const int colBase = wave * (OTC * 16);

    v4f acc[5][OTC][2];
    #pragma unroll
    for (int j = 0; j < 5; ++j)
        #pragma unroll
        for (int ct = 0; ct < OTC; ++ct)
            #pragma unroll
            for (int rt = 0; rt < 2; ++rt)
                acc[j][ct][rt] = (v4f){0.f, 0.f, 0.f, 0.f};

    Frag wf[2][NW];
    #pragma unroll
    for (int i = 0; i < NW; ++i) wf[0][i] = wpre[i];

    Frag xS[8];
    if constexpr (SHARED_IN) {
        #pragma unroll
        for (int ks = 0; ks < 4; ++ks) {
            const int gg = ks * 4 + quad;
            #pragma unroll
            for (int rt = 0; rt < 2; ++rt) {
                const int row = rt * 16 + l15;
                xS[ks * 2 + rt].q =
                    *(const uint4*)(lds + inOff + row * 256 + ((gg ^ (row & 15)) << 4));
            }
        }
    }

    #pragma unroll
    for (int j = 0; j < 5; ++j) {
        int sj = j + wave; if (sj >= 5) sj -= 5;
        if (j < 4) {                       // prefetch weights for stream j+1
            int sn = sj + 1; if (sn >= 5) sn -= 5;
            const unsigned short* Wn = W + sn * (N * 128);
            #pragma unroll
            for (int ct = 0; ct < OTC; ++ct)
                #pragma unroll
                for (int ks = 0; ks < 4; ++ks)
                    wf[(j + 1) & 1][ct * 4 + ks].q =
                        *(const uint4*)(Wn + (colBase + ct * 16 + l15) * 128
                                        + ks * 32 + quad * 8);
        }
        Frag xf[8];
        if constexpr (!SHARED_IN) {
            #pragma unroll
            for (int ks = 0; ks < 4; ++ks) {
                const int gg = ks * 4 + quad;
                #pragma unroll
                for (int rt = 0; rt < 2; ++rt) {
                    const int row = rt * 16 + l15;
                    xf[ks * 2 + rt].q = *(const uint4*)(lds + inOff + sj * SLOT
                                         + row * 256 + ((gg ^ (row & 15)) << 4));
                }
            }
        }
        #pragma unroll
        for (int ks = 0; ks < 4; ++ks)
            #pragma unroll
            for (int rt = 0; rt < 2; ++rt)
                #pragma unroll
                for (int ct = 0; ct < OTC; ++ct)
                    acc[j][ct][rt] = __builtin_amdgcn_mfma_f32_16x16x32_bf16(
                        wf[j & 1][ct * 4 + ks].v,
                        (SHARED_IN ? xS[ks * 2 + rt].v : xf[ks * 2 + rt].v),
                        acc[j][ct][rt], 0, 0, 0);
    }

    // ---- epilogue: uniform rotated combine ----
    v4f vr[OTC][2];
    #pragma unroll
    for (int ct = 0; ct < OTC; ++ct)
        #pragma unroll
        for (int rt = 0; rt < 2; ++rt)
            vr[ct][rt] = (v4f){0.f, 0.f, 0.f, 0.f};

    #pragma unroll
    for (int j = 0; j < 5; ++j) {
        int sj = j + wave; if (sj >= 5) sj -= 5;
        const float* bp = (sj == 0) ? mbias : tbias + (sj - 1) * N;
        #pragma unroll
        for (int ct = 0; ct < OTC; ++ct) {
            const int ob = colBase + ct * 16 + quad * 4;
            const float4 bb = *(const float4*)(bp + ob);
            #pragma unroll
            for (int rt = 0; rt < 2; ++rt) {
                float t0 = acc[j][ct][rt][0] + bb.x;
                float t1 = acc[j][ct][rt][1] + bb.y;
                float t2 = acc[j][ct][rt][2] + bb.z;
                float t3 = acc[j][ct][rt][3] + bb.w;
                vr[ct][rt][0] = fmaf(coef[j], t0, vr[ct][rt][0]);
                vr[ct][rt][1] = fmaf(coef[j], t1, vr[ct][rt][1]);
                vr[ct][rt][2] = fmaf(coef[j], t2, vr[ct][rt][2]);
                vr[ct][rt][3] = fmaf(coef[j], t3, vr[ct][rt][3]);
                if (!FINAL && sj != 0) {        // teacher relu'd pre-act -> slot sj
                    const int row = rt * 16 + l15;
                    *(uint2*)(lds + outOff + sj * SLOT + row * 256
                              + (((ob >> 3) ^ (row & 15)) << 4) + ((ob & 7) << 1)) =
                        make_uint2(pack2(fmaxf(t0, 0.f), fmaxf(t1, 0.f)),
                                   pack2(fmaxf(t2, 0.f), fmaxf(t3, 0.f)));
                }
            }
        }
    }

    if constexpr (!FINAL) {
        #pragma unroll
        for (int ct = 0; ct < OTC; ++ct) {
            const int ob = colBase + ct * 16 + quad * 4;
            #pragma unroll
            for (int rt = 0; rt < 2; ++rt) {
                const int row = rt * 16 + l15;
                *(uint2*)(lds + outOff + row * 256
                          + (((ob >> 3) ^ (row & 15)) << 4) + ((ob & 7) << 1)) =
                    make_uint2(pack2(fmaxf(vr[ct][rt][0], 0.f), fmaxf(vr[ct][rt][1], 0.f)),
                               pack2(fmaxf(vr[ct][rt][2], 0.f), fmaxf(vr[ct][rt][3], 0.f)));
            }
        }
    } else {
        const float4 wo = *(const float4*)(Wout + colBase + quad * 4);
        #pragma unroll
        for (int rt = 0; rt < 2; ++rt) {
            float pp = fmaxf(vr[0][rt][0], 0.f) * wo.x + fmaxf(vr[0][rt][1], 0.f) * wo.y
                     + fmaxf(vr[0][rt][2], 0.f) * wo.z + fmaxf(vr[0][rt][3], 0.f) * wo.w;
            pp += __shfl_xor(pp, 16);
            pp += __shfl_xor(pp, 32);
            if (lane < 16)
                pgrid[wave * 32 + rt * 16 + lane] = pp;
        }
    }
}

extern "C" __global__ __launch_bounds__(256, 2)
void critic_kernel(KParams p)
{
    extern __shared__ char lds[];
    const int tid  = threadIdx.x;
    const int lane = tid & 63;
    const int wave = tid >> 6;
    const int head = blockIdx.x & 1;                 // one head per block
    const int rowBase = (blockIdx.x >> 1) * TB;

    const float m  = p.mix[0];
    float coef[5];
    #pragma unroll
    for (int j = 0; j < 5; ++j) {
        int s = j + wave; if (s >= 5) s -= 5;
        coef[j] = (s == 0) ? (1.f - m) : m * p.P[s - 1];
    }

    const unsigned short* wb = p.wbf + head * HEAD_W;
    const int hb = head * 3;

    Frag w1[8];
    preload<128>(w1, wb, lane, wave);
    stage_xu(lds, p.x, p.u, rowBase, tid);
    __syncthreads();
    // L1: xu (BUF0.slot0, shared) -> BUF1 (slot0 = combined+relu, 1-4 = teacher relu)
    compute<true, false, 128>(lds, 0, BUF1, w1, wb, p.mb[hb + 0], p.tb[hb + 0],
                              coef, lane, wave, nullptr, nullptr);

    Frag w2[8];
    preload<128>(w2, wb + 81920, lane, wave);
    __syncthreads();
    // L2: BUF1 -> BUF0 (overwrites xu)
    compute<false, false, 128>(lds, BUF1, 0, w2, wb + 81920, p.mb[hb + 1], p.tb[hb + 1],
                               coef, lane, wave, nullptr, nullptr);

    Frag w3[8];
    preload<64>(w3, wb + 163840, lane, wave);
    __syncthreads();
    // L3 + L4 fused: BUF0 -> register combine -> dot(Wout) -> pgrid (in BUF1)
    compute<false, true, 64>(lds, 0, 0, w3, wb + 163840, p.mb[hb + 2], p.tb[hb + 2],
                             coef, lane, wave, p.Wout[head], (float*)(lds + BUF1));
    __syncthreads();

    if (tid < TB) {
        const float* pg = (const float*)(lds + BUF1);
        p.out[head * B_TOTAL + rowBase + tid] =
            p.bout[head][0] + pg[tid] + pg[32 + tid] + pg[64 + tid] + pg[96 + tid];
    }
}

extern "C" void kernel_launch(void* const* d_in, const int* in_sizes, int n_in,
                              void* d_out, int out_size, void* d_ws, size_t ws_size,
                              hipStream_t stream)
{
    (void)in_sizes; (void)n_in; (void)out_size; (void)ws_size;

    PrepParams pp;
    const int sidx[12] = {4, 20, 6, 22, 8, 24, 12, 26, 14, 28, 16, 30};
    for (int i = 0; i < 12; ++i) pp.src[i] = (const float*)d_in[sidx[i]];
    pp.dst = (unsigned short*)d_ws;

    KParams kp;
    kp.x = (const float*)d_in[0];  kp.u = (const float*)d_in[1];
    kp.mix = (const float*)d_in[2]; kp.P = (const float*)d_in[3];
    const int mbi[6] = {5, 7, 9, 13, 15, 17};
    const int tbi[6] = {21, 23, 25, 27, 29, 31};
    for (int i = 0; i < 6; ++i) {
        kp.mb[i] = (const float*)d_in[mbi[i]];
        kp.tb[i] = (const float*)d_in[tbi[i]];
    }
    kp.Wout[0] = (const float*)d_in[10]; kp.Wout[1] = (const float*)d_in[18];
    kp.bout[0] = (const float*)d_in[11]; kp.bout[1] = (const float*)d_in[19];
    kp.wbf = (const unsigned short*)d_ws;
    kp.out = (float*)d_out;

    (void)hipFuncSetAttribute((const void*)critic_kernel,
                              hipFuncAttributeMaxDynamicSharedMemorySize, LDS_BYTES);

    hipLaunchKernelGGL(prep_kernel, dim3(400), dim3(256), 0, stream, pp);
    hipLaunchKernelGGL(critic_kernel, dim3(16384), dim3(256), LDS_BYTES, stream, kp);
}